// Round 2
// baseline (641.598 us; speedup 1.0000x reference)
//
#include <hip/hip_runtime.h>
#include <hip/hip_bf16.h>
#include <cstddef>

// Problem constants (must match reference)
#define BN   1024   // B
#define NEGN 5      // NEG
#define NBRN 50     // NBR
#define DN   128    // D
#define EN   4      // E
#define APAD 132    // padded LDS row stride (floats): 132%32==4 -> spreads banks; 16B aligned
#define NEG_INF_F (-4294967295.0f)

__device__ __forceinline__ float leaky_f(float x) { return x >= 0.0f ? x : 0.01f * x; }

__device__ __forceinline__ float wave_sum(float v) {
#pragma unroll
    for (int off = 32; off; off >>= 1) v += __shfl_xor(v, off, 64);
    return v;
}
__device__ __forceinline__ float wave_max(float v) {
#pragma unroll
    for (int off = 32; off; off >>= 1) v = fmaxf(v, __shfl_xor(v, off, 64));
    return v;
}
__device__ __forceinline__ float sigmoid_f(float x) {
    if (x >= 0.0f) { float z = __expf(-x); return 1.0f / (1.0f + z); }
    float z = __expf(x); return z / (1.0f + z);
}

// ---------------------------------------------------------------------------
// Kernel 1: node latents  leaky(emb[id] @ W_node + b_node) for
// s_ids(B), t_ids(B), s_negs(B*NEG), t_negs(B*NEG)  -> 12288 rows, 8 per block
// ---------------------------------------------------------------------------
__global__ __launch_bounds__(128) void latent_kernel(
    const float* __restrict__ emb, const float* __restrict__ W, const float* __restrict__ bias,
    const int* __restrict__ s_ids, const int* __restrict__ t_ids,
    const int* __restrict__ s_negs, const int* __restrict__ t_negs,
    float* __restrict__ sE, float* __restrict__ tE,
    float* __restrict__ negS, float* __restrict__ negT)
{
    const int tid = threadIdx.x;           // 0..127 = output col
    const int r0 = blockIdx.x * 8;
    __shared__ float rows[8][DN];
    __shared__ int ids_l[8];

    if (tid < 8) {
        int r = r0 + tid;
        int id;
        if (r < BN)                       id = s_ids[r];
        else if (r < 2 * BN)              id = t_ids[r - BN];
        else if (r < 2 * BN + BN * NEGN)  id = s_negs[r - 2 * BN];
        else                              id = t_negs[r - 2 * BN - BN * NEGN];
        ids_l[tid] = id;
    }
    __syncthreads();
#pragma unroll
    for (int r8 = 0; r8 < 8; ++r8)
        rows[r8][tid] = emb[(size_t)ids_l[r8] * DN + tid];
    __syncthreads();

    float acc[8];
#pragma unroll
    for (int r8 = 0; r8 < 8; ++r8) acc[r8] = 0.0f;

    for (int i0 = 0; i0 < DN; i0 += 4) {
        const float w0 = W[(i0 + 0) * DN + tid];
        const float w1 = W[(i0 + 1) * DN + tid];
        const float w2 = W[(i0 + 2) * DN + tid];
        const float w3 = W[(i0 + 3) * DN + tid];
#pragma unroll
        for (int r8 = 0; r8 < 8; ++r8) {
            const float4 a = *reinterpret_cast<const float4*>(&rows[r8][i0]);
            acc[r8] = fmaf(a.x, w0, fmaf(a.y, w1, fmaf(a.z, w2, fmaf(a.w, w3, acc[r8]))));
        }
    }
    const float bb = bias[tid];
#pragma unroll
    for (int r8 = 0; r8 < 8; ++r8) {
        const int r = r0 + r8;
        const float v = leaky_f(acc[r8] + bb);
        float* dst;
        if (r < BN)                       dst = sE   + (size_t)r * DN;
        else if (r < 2 * BN)              dst = tE   + (size_t)(r - BN) * DN;
        else if (r < 2 * BN + BN * NEGN)  dst = negS + (size_t)(r - 2 * BN) * DN;
        else                              dst = negT + (size_t)(r - 2 * BN - BN * NEGN) * DN;
        dst[tid] = v;
    }
}

// ---------------------------------------------------------------------------
// Kernel 2: per (side,e,b): neighbor latents, distances, masked softmax,
// pos/neg attention sums, hete scalar.  grid = 2*E*B = 8192 blocks x 256 thr.
// ---------------------------------------------------------------------------
__global__ __launch_bounds__(256) void edge_kernel(
    const float* __restrict__ emb, const float* __restrict__ ete,
    const float* __restrict__ Wn, const float* __restrict__ bn,
    const float* __restrict__ Wa, const float* __restrict__ ba,
    const int* __restrict__ s_nbr_ids, const int* __restrict__ s_nbr_masks, const float* __restrict__ s_nbr_w,
    const int* __restrict__ t_nbr_ids, const int* __restrict__ t_nbr_masks, const float* __restrict__ t_nbr_w,
    const float* __restrict__ sE, const float* __restrict__ tE,
    const float* __restrict__ negS, const float* __restrict__ negT,
    float* __restrict__ posW, float* __restrict__ heteW, float* __restrict__ negW)
{
    const int bid  = blockIdx.x;
    const int b    = bid & (BN - 1);
    const int e    = (bid >> 10) & 3;
    const int side = bid >> 12;

    const int*   ids_p;  const int* mask_p; const float* w_p;
    const float* node_p; const float* tgt_p; const float* negs_p;
    if (side == 0) { ids_p = s_nbr_ids; mask_p = s_nbr_masks; w_p = s_nbr_w;
                     node_p = sE; tgt_p = tE; negs_p = negT; }
    else           { ids_p = t_nbr_ids; mask_p = t_nbr_masks; w_p = t_nbr_w;
                     node_p = tE; tgt_p = sE; negs_p = negS; }
    const int base = (e * BN + b) * NBRN;

    __shared__ float A[NBRN * APAD];       // emb rows, later overwritten with nbr latents
    __shared__ float npe[DN], tgt[DN], negv[NEGN][DN];
    __shared__ float red[NBRN][2][7];      // per-j per-col-half reduction partials
    __shared__ float atts_l[NBRN];
    __shared__ float misc[4];
    __shared__ int   ids_l[NBRN];

    const int tid = threadIdx.x;
    const int col = tid & 127;
    const int g   = tid >> 7;      // neighbor parity handled by this thread

    if (tid < NBRN) ids_l[tid] = ids_p[base + tid];
    if (tid < DN) {
        npe[tid] = node_p[(size_t)b * DN + tid] + ete[e * DN + tid];
        tgt[tid] = tgt_p[(size_t)b * DN + tid];
    }
    for (int idx = tid; idx < NEGN * DN; idx += 256) {
        const int n = idx >> 7, c = idx & 127;
        negv[n][c] = negs_p[((size_t)b * NEGN + n) * DN + c];
    }
    __syncthreads();
    for (int idx = tid; idx < NBRN * DN; idx += 256) {
        const int j = idx >> 7, c = idx & 127;
        A[j * APAD + c] = emb[(size_t)ids_l[j] * DN + c];
    }
    __syncthreads();

    // GEMM: acc[r] = sum_i A[2r+g][i] * Wn[i][col]
    float acc[25];
#pragma unroll
    for (int r = 0; r < 25; ++r) acc[r] = 0.0f;
    for (int i0 = 0; i0 < DN; i0 += 4) {
        const float w0 = Wn[(i0 + 0) * DN + col];
        const float w1 = Wn[(i0 + 1) * DN + col];
        const float w2 = Wn[(i0 + 2) * DN + col];
        const float w3 = Wn[(i0 + 3) * DN + col];
#pragma unroll
        for (int r = 0; r < 25; ++r) {
            const float4 a = *reinterpret_cast<const float4*>(&A[(2 * r + g) * APAD + i0]);
            acc[r] = fmaf(a.x, w0, fmaf(a.y, w1, fmaf(a.z, w2, fmaf(a.w, w3, acc[r]))));
        }
    }
    __syncthreads();   // all GEMM reads of A done before we overwrite it

    // Epilogue: bias+leaky, store nbr into A, per-j distance reductions
    const float bb    = bn[col];
    const float npe_c = npe[col];
    const float tgt_c = tgt[col];
    float ngc[NEGN];
#pragma unroll
    for (int n = 0; n < NEGN; ++n) ngc[n] = negv[n][col];
    const int half = col >> 6;     // which 64-col half this wave covers

#pragma unroll
    for (int r = 0; r < 25; ++r) {
        const int j = 2 * r + g;
        const float v = leaky_f(acc[r] + bb);
        A[j * APAD + col] = v;
        float d0 = npe_c - v; d0 *= d0;
        float d1 = v - tgt_c; d1 *= d1;
        float s0 = wave_sum(d0);
        float s1 = wave_sum(d1);
        float sn[NEGN];
#pragma unroll
        for (int n = 0; n < NEGN; ++n) {
            float dv = v - ngc[n];
            sn[n] = wave_sum(dv * dv);
        }
        if ((tid & 63) == 0) {
            red[j][half][0] = s0;
            red[j][half][1] = s1;
#pragma unroll
            for (int n = 0; n < NEGN; ++n) red[j][half][2 + n] = sn[n];
        }
    }
    __syncthreads();

    // Softmax + pos/neg sums: single wave, lane j handles neighbor j
    if (tid < 64) {
        const int j = tid;
        const bool act = j < NBRN;
        float dj = NEG_INF_F, mut = 0.0f, wj = 0.0f;
        float mn[NEGN];
#pragma unroll
        for (int n = 0; n < NEGN; ++n) mn[n] = 0.0f;
        int mk = 0;
        float x = NEG_INF_F;
        if (act) {
            dj  = -(red[j][0][0] + red[j][1][0]);
            mut = -(red[j][0][1] + red[j][1][1]);
#pragma unroll
            for (int n = 0; n < NEGN; ++n) mn[n] = -(red[j][0][2 + n] + red[j][1][2 + n]);
            mk = mask_p[base + j];
            wj = w_p[base + j];
            x = mk ? dj : NEG_INF_F;
        }
        const float m  = wave_max(x);
        const float ex = act ? __expf(x - m) : 0.0f;   // exactly 50 summands, like the reference
        const float S  = wave_sum(ex);
        const float atts  = ex / S;
        const float atts2 = (act && mk) ? atts : 0.0f;
        const float nw = atts2 * wj;
        const float posv = wave_sum(nw * mut);
        float nsum[NEGN];
#pragma unroll
        for (int n = 0; n < NEGN; ++n) nsum[n] = wave_sum(nw * mn[n]);
        const float wsum = wave_sum(act ? wj : 0.0f);
        const float msum = wave_sum(act ? (float)mk : 0.0f);
        if (act) atts_l[j] = atts2;
        if (tid == 0) {
            const float nbr_n = fminf(fmaxf(msum, 1.0f), (float)NBRN);
            misc[0] = wsum / nbr_n;   // ave_w
            const int o = (side * EN + e) * BN + b;
            posW[o] = posv;
#pragma unroll
            for (int n = 0; n < NEGN; ++n) negW[(size_t)o * NEGN + n] = nsum[n];
        }
    }
    __syncthreads();

    // avg_embed dot W_att (hete scalar)
    if (tid < DN) {
        float sacc = 0.0f;
#pragma unroll 5
        for (int j = 0; j < NBRN; ++j) sacc += atts_l[j] * A[j * APAD + tid];
        const float p = sacc * Wa[tid];
        const float ps = wave_sum(p);
        if ((tid & 63) == 0) misc[1 + (tid >> 6)] = ps;
    }
    __syncthreads();
    if (tid == 0) {
        const float tot = misc[0] * (misc[1] + misc[2]) + ba[0];
        heteW[(side * EN + e) * BN + b] = leaky_f(tot);
    }
}

// ---------------------------------------------------------------------------
// Kernel 3: allpos[side][e] = all_b(flags[e][b] > 0)
// ---------------------------------------------------------------------------
__global__ __launch_bounds__(256) void allpos_kernel(
    const int* __restrict__ s_flags, const int* __restrict__ t_flags, int* __restrict__ allpos)
{
    const int side = blockIdx.x >> 2, e = blockIdx.x & 3;
    const int* f = side ? t_flags : s_flags;
    int ok = 1;
    for (int b = threadIdx.x; b < BN; b += 256) ok &= (f[e * BN + b] > 0);
    ok = __syncthreads_and(ok);
    if (threadIdx.x == 0) allpos[blockIdx.x] = ok;
}

// ---------------------------------------------------------------------------
// Kernel 4: per-b loss partial (mu, neg_mus, double-softmax over E, log-sigmoids)
// ---------------------------------------------------------------------------
__global__ __launch_bounds__(64) void loss_kernel(
    const int* __restrict__ e_types, const float* __restrict__ ete,
    const int* __restrict__ s_flags, const int* __restrict__ t_flags,
    const float* __restrict__ sE, const float* __restrict__ tE,
    const float* __restrict__ negS, const float* __restrict__ negT,
    const float* __restrict__ posW, const float* __restrict__ heteW,
    const float* __restrict__ negW, const int* __restrict__ allpos,
    float* __restrict__ partials)
{
    const int b = blockIdx.x;
    const int lane = threadIdx.x;   // 64 lanes, each covers dims lane and lane+64
    const int et = e_types[b];

    const float se0 = sE[(size_t)b * DN + lane],      se1 = sE[(size_t)b * DN + lane + 64];
    const float te0 = tE[(size_t)b * DN + lane],      te1 = tE[(size_t)b * DN + lane + 64];
    const float ee0 = ete[et * DN + lane],            ee1 = ete[et * DN + lane + 64];

    float d0 = se0 + ee0 - te0, d1 = se1 + ee1 - te1;
    const float mu = -wave_sum(d0 * d0 + d1 * d1);

    float nmst[NEGN], nmts[NEGN];
#pragma unroll
    for (int n = 0; n < NEGN; ++n) {
        const float* nt = negT + ((size_t)b * NEGN + n) * DN;
        const float* ns = negS + ((size_t)b * NEGN + n) * DN;
        float a0 = se0 - nt[lane], a1 = se1 - nt[lane + 64];
        nmst[n] = -wave_sum(a0 * a0 + a1 * a1);
        float c0 = te0 - ns[lane], c1 = te1 - ns[lane + 64];
        nmts[n] = -wave_sum(c0 * c0 + c1 * c1);
    }

    if (lane == 0) {
        float posl[2];
        float negl[2][NEGN];
        for (int side = 0; side < 2; ++side) {
            const int* fl = side ? t_flags : s_flags;
            float att[EN], pv[EN];
            int mk[EN], ap[EN];
#pragma unroll
            for (int ei = 0; ei < EN; ++ei) {
                ap[ei] = allpos[side * EN + ei];
                mk[ei] = fl[ei * BN + b] > 0;
                const int o = (side * EN + ei) * BN + b;
                att[ei] = ap[ei] ? 0.0f : heteW[o];
                pv[ei]  = ap[ei] ? 0.0f : posW[o];
            }
            // softmax 1: where(mask, att, NEG_INF)
            float x[EN], m = NEG_INF_F;
#pragma unroll
            for (int ei = 0; ei < EN; ++ei) { x[ei] = mk[ei] ? att[ei] : NEG_INF_F; m = fmaxf(m, x[ei]); }
            float s = 0.0f, ex[EN];
#pragma unroll
            for (int ei = 0; ei < EN; ++ei) { ex[ei] = __expf(x[ei] - m); s += ex[ei]; }
            float v1[EN];
#pragma unroll
            for (int ei = 0; ei < EN; ++ei) v1[ei] = ex[ei] / s;
            // softmax 2: softmax(where(mask, v1, 0.0))  (no output masking!)
            float y[EN], m2 = NEG_INF_F;
#pragma unroll
            for (int ei = 0; ei < EN; ++ei) { y[ei] = mk[ei] ? v1[ei] : 0.0f; m2 = fmaxf(m2, y[ei]); }
            float s2 = 0.0f, ex2[EN];
#pragma unroll
            for (int ei = 0; ei < EN; ++ei) { ex2[ei] = __expf(y[ei] - m2); s2 += ex2[ei]; }
            float pl = 0.0f;
            float nl[NEGN];
#pragma unroll
            for (int n = 0; n < NEGN; ++n) nl[n] = 0.0f;
#pragma unroll
            for (int ei = 0; ei < EN; ++ei) {
                const float na = ex2[ei] / s2;
                pl += na * pv[ei];
                const int o = (side * EN + ei) * BN + b;
#pragma unroll
                for (int n = 0; n < NEGN; ++n) {
                    const float nv = ap[ei] ? 0.0f : negW[(size_t)o * NEGN + n];
                    nl[n] += na * nv;
                }
            }
            posl[side] = pl;
#pragma unroll
            for (int n = 0; n < NEGN; ++n) negl[side][n] = nl[n];
        }

        const float lam = mu + posl[0] + posl[1];
        float total = -logf(sigmoid_f(lam) + 1e-6f) / (float)BN;
#pragma unroll
        for (int n = 0; n < NEGN; ++n) {
            total += -logf(sigmoid_f(-(nmst[n] + negl[0][n])) + 1e-6f) / (float)(BN * NEGN);
            total += -logf(sigmoid_f(-(nmts[n] + negl[1][n])) + 1e-6f) / (float)(BN * NEGN);
        }
        partials[b] = total;
    }
}

// ---------------------------------------------------------------------------
// Kernel 5: reduce partials + NORM_RATE * sum(ete^2) -> d_out[0]
// ---------------------------------------------------------------------------
__global__ __launch_bounds__(256) void final_kernel(
    const float* __restrict__ partials, const float* __restrict__ ete, float* __restrict__ out)
{
    __shared__ float red[256];
    const int tid = threadIdx.x;
    float s = 0.0f;
    for (int i = tid; i < BN; i += 256) s += partials[i];
    float t = 0.0f;
    for (int i = tid; i < EN * DN; i += 256) { const float v = ete[i]; t += v * v; }
    red[tid] = s + 1e-4f * t;
    __syncthreads();
    for (int st = 128; st > 0; st >>= 1) {
        if (tid < st) red[tid] += red[tid + st];
        __syncthreads();
    }
    if (tid == 0) out[0] = red[0];
}

// ---------------------------------------------------------------------------
extern "C" void kernel_launch(void* const* d_in, const int* in_sizes, int n_in,
                              void* d_out, int out_size, void* d_ws, size_t ws_size,
                              hipStream_t stream)
{
    const int*   e_types   = (const int*)  d_in[0];
    const int*   s_ids     = (const int*)  d_in[1];
    // d_in[2] s_types: inert
    const int*   s_negs    = (const int*)  d_in[3];
    const int*   s_nbr_ids = (const int*)  d_in[4];
    const int*   s_nbr_msk = (const int*)  d_in[5];
    const float* s_nbr_w   = (const float*)d_in[6];
    const int*   s_flags   = (const int*)  d_in[7];
    const int*   t_ids     = (const int*)  d_in[8];
    // d_in[9] t_types: inert
    const int*   t_negs    = (const int*)  d_in[10];
    const int*   t_nbr_ids = (const int*)  d_in[11];
    const int*   t_nbr_msk = (const int*)  d_in[12];
    const float* t_nbr_w   = (const float*)d_in[13];
    const int*   t_flags   = (const int*)  d_in[14];
    const float* emb       = (const float*)d_in[15];
    const float* ete       = (const float*)d_in[16];
    const float* W_node    = (const float*)d_in[17];
    const float* b_node    = (const float*)d_in[18];
    const float* W_nbr     = (const float*)d_in[19];
    const float* b_nbr     = (const float*)d_in[20];
    const float* W_att     = (const float*)d_in[21];
    const float* b_att     = (const float*)d_in[22];

    // workspace layout (floats)
    float* ws   = (float*)d_ws;
    float* sE   = ws;                                   // B*D
    float* tE   = sE   + (size_t)BN * DN;               // B*D
    float* negS = tE   + (size_t)BN * DN;               // B*NEG*D
    float* negT = negS + (size_t)BN * NEGN * DN;        // B*NEG*D
    float* posW = negT + (size_t)BN * NEGN * DN;        // 2*E*B
    float* heteW= posW + (size_t)2 * EN * BN;           // 2*E*B
    float* negW = heteW+ (size_t)2 * EN * BN;           // 2*E*B*NEG
    float* parts= negW + (size_t)2 * EN * BN * NEGN;    // B
    int*   apos = (int*)(parts + BN);                   // 8

    latent_kernel<<<(2 * BN + 2 * BN * NEGN) / 8, 128, 0, stream>>>(
        emb, W_node, b_node, s_ids, t_ids, s_negs, t_negs, sE, tE, negS, negT);

    edge_kernel<<<2 * EN * BN, 256, 0, stream>>>(
        emb, ete, W_nbr, b_nbr, W_att, b_att,
        s_nbr_ids, s_nbr_msk, s_nbr_w,
        t_nbr_ids, t_nbr_msk, t_nbr_w,
        sE, tE, negS, negT, posW, heteW, negW);

    allpos_kernel<<<8, 256, 0, stream>>>(s_flags, t_flags, apos);

    loss_kernel<<<BN, 64, 0, stream>>>(
        e_types, ete, s_flags, t_flags, sE, tE, negS, negT,
        posW, heteW, negW, apos, parts);

    final_kernel<<<1, 256, 0, stream>>>(parts, ete, (float*)d_out);
}

// Round 3
// 193.438 us; speedup vs baseline: 3.3168x; 3.3168x over previous
//
#include <hip/hip_runtime.h>
#include <hip/hip_bf16.h>
#include <cstddef>

// Problem constants (must match reference)
#define BN   1024   // B
#define NEGN 5      // NEG
#define NBRN 50     // NBR
#define DN   128    // D
#define EN   4      // E
#define MPAD 64     // padded neighbor-row count for MFMA tiles
#define NEG_INF_F (-4294967295.0f)

typedef __bf16 bf16_t;
typedef __bf16 bf16x8 __attribute__((ext_vector_type(8)));
typedef __bf16 bf16x4 __attribute__((ext_vector_type(4)));
typedef float  f32x4  __attribute__((ext_vector_type(4)));

__device__ __forceinline__ float leaky_f(float x) { return x >= 0.0f ? x : 0.01f * x; }

__device__ __forceinline__ float wave_sum(float v) {
#pragma unroll
    for (int off = 32; off; off >>= 1) v += __shfl_xor(v, off, 64);
    return v;
}
__device__ __forceinline__ float wave_max(float v) {
#pragma unroll
    for (int off = 32; off; off >>= 1) v = fmaxf(v, __shfl_xor(v, off, 64));
    return v;
}
__device__ __forceinline__ float sigmoid_f(float x) {
    if (x >= 0.0f) { float z = __expf(-x); return 1.0f / (1.0f + z); }
    float z = __expf(x); return z / (1.0f + z);
}

// ---------------------------------------------------------------------------
// Kernel 0: prep — WnT_bf16[n][k] = bf16(W_nbr[k][n])  (16384 elems, runs once
// per launch, ~µs). Read directly from L2 by edge_kernel MFMA B-frags.
// ---------------------------------------------------------------------------
__global__ __launch_bounds__(256) void prep_kernel(
    const float* __restrict__ Wn, bf16_t* __restrict__ WnT)
{
    const int idx = blockIdx.x * 256 + threadIdx.x;
    if (idx < DN * DN) {
        const int n = idx >> 7, k = idx & 127;
        WnT[idx] = (bf16_t)Wn[k * DN + n];
    }
}

// ---------------------------------------------------------------------------
// Kernel 1: node latents  leaky(emb[id] @ W_node + b_node)  (fp32, unchanged)
// ---------------------------------------------------------------------------
__global__ __launch_bounds__(128) void latent_kernel(
    const float* __restrict__ emb, const float* __restrict__ W, const float* __restrict__ bias,
    const int* __restrict__ s_ids, const int* __restrict__ t_ids,
    const int* __restrict__ s_negs, const int* __restrict__ t_negs,
    float* __restrict__ sE, float* __restrict__ tE,
    float* __restrict__ negS, float* __restrict__ negT)
{
    const int tid = threadIdx.x;           // 0..127 = output col
    const int r0 = blockIdx.x * 8;
    __shared__ float rows[8][DN];
    __shared__ int ids_l[8];

    if (tid < 8) {
        int r = r0 + tid;
        int id;
        if (r < BN)                       id = s_ids[r];
        else if (r < 2 * BN)              id = t_ids[r - BN];
        else if (r < 2 * BN + BN * NEGN)  id = s_negs[r - 2 * BN];
        else                              id = t_negs[r - 2 * BN - BN * NEGN];
        ids_l[tid] = id;
    }
    __syncthreads();
#pragma unroll
    for (int r8 = 0; r8 < 8; ++r8)
        rows[r8][tid] = emb[(size_t)ids_l[r8] * DN + tid];
    __syncthreads();

    float acc[8];
#pragma unroll
    for (int r8 = 0; r8 < 8; ++r8) acc[r8] = 0.0f;

    for (int i0 = 0; i0 < DN; i0 += 4) {
        const float w0 = W[(i0 + 0) * DN + tid];
        const float w1 = W[(i0 + 1) * DN + tid];
        const float w2 = W[(i0 + 2) * DN + tid];
        const float w3 = W[(i0 + 3) * DN + tid];
#pragma unroll
        for (int r8 = 0; r8 < 8; ++r8) {
            const float4 a = *reinterpret_cast<const float4*>(&rows[r8][i0]);
            acc[r8] = fmaf(a.x, w0, fmaf(a.y, w1, fmaf(a.z, w2, fmaf(a.w, w3, acc[r8]))));
        }
    }
    const float bb = bias[tid];
#pragma unroll
    for (int r8 = 0; r8 < 8; ++r8) {
        const int r = r0 + r8;
        const float v = leaky_f(acc[r8] + bb);
        float* dst;
        if (r < BN)                       dst = sE   + (size_t)r * DN;
        else if (r < 2 * BN)              dst = tE   + (size_t)(r - BN) * DN;
        else if (r < 2 * BN + BN * NEGN)  dst = negS + (size_t)(r - 2 * BN) * DN;
        else                              dst = negT + (size_t)(r - 2 * BN - BN * NEGN) * DN;
        dst[tid] = v;
    }
}

// ---------------------------------------------------------------------------
// Kernel 2: per (side,e,b) edge block — MFMA version.
//   GEMM1 (MFMA): L = leaky(Eg @ Wn + bn)            [64x128 tiles]
//   GEMM2 (MFMA): dots = L @ [npe,tgt,neg0..4,Wa]^T  [64x8]
//   distances via -||x-y||^2 = 2 x.y - ||x||^2 - ||y||^2  (norms exact fp32)
// grid = 2*E*B = 8192 blocks x 256 thr (4 waves; wave w owns rows 16w..16w+15)
// ---------------------------------------------------------------------------
__global__ __launch_bounds__(256) void edge_kernel(
    const float* __restrict__ emb, const float* __restrict__ ete,
    const bf16_t* __restrict__ WnT, const float* __restrict__ bn,
    const float* __restrict__ Wa, const float* __restrict__ ba,
    const int* __restrict__ s_nbr_ids, const int* __restrict__ s_nbr_masks, const float* __restrict__ s_nbr_w,
    const int* __restrict__ t_nbr_ids, const int* __restrict__ t_nbr_masks, const float* __restrict__ t_nbr_w,
    const float* __restrict__ sE, const float* __restrict__ tE,
    const float* __restrict__ negS, const float* __restrict__ negT,
    float* __restrict__ posW, float* __restrict__ heteW, float* __restrict__ negW)
{
    const int bid  = blockIdx.x;
    const int b    = bid & (BN - 1);
    const int e    = (bid >> 10) & 3;
    const int side = bid >> 12;

    const int*   ids_p;  const int* mask_p; const float* w_p;
    const float* node_p; const float* tgt_p; const float* negs_p;
    if (side == 0) { ids_p = s_nbr_ids; mask_p = s_nbr_masks; w_p = s_nbr_w;
                     node_p = sE; tgt_p = tE; negs_p = negT; }
    else           { ids_p = t_nbr_ids; mask_p = t_nbr_masks; w_p = t_nbr_w;
                     node_p = tE; tgt_p = sE; negs_p = negS; }
    const int base = (e * BN + b) * NBRN;

    // LDS: swizzled bf16 tiles (elem-index XOR: col ^ ((row&7)<<3) within row)
    __shared__ __align__(16) bf16_t EgL[MPAD * DN];  // emb rows, then L (reused)
    __shared__ __align__(16) bf16_t VT[16 * DN];     // rows 0..7 = npe,tgt,neg0..4,Wa
    __shared__ float dotL[MPAD][17];
    __shared__ float n2_l[MPAD];
    __shared__ float norm_l[8];
    __shared__ int   ids_l[NBRN];

    const int tid  = threadIdx.x;
    const int lane = tid & 63;
    const int w    = tid >> 6;       // wave id 0..3 -> owns rows 16w..16w+15
    const int l15  = lane & 15;
    const int l4   = lane >> 4;

    if (tid < NBRN) ids_l[tid] = ids_p[base + tid];

    // ---- phase 0: build VT (bf16, swizzled) + exact fp32 norms ----
    {
        const int q = tid >> 5, c4 = tid & 31;   // q 0..7, 4 floats per thread
        float v[4];
#pragma unroll
        for (int i = 0; i < 4; ++i) {
            const int c = c4 * 4 + i;
            float x;
            if (q == 0)      x = node_p[(size_t)b * DN + c] + ete[e * DN + c];
            else if (q == 1) x = tgt_p[(size_t)b * DN + c];
            else if (q < 7)  x = negs_p[((size_t)b * NEGN + (q - 2)) * DN + c];
            else             x = Wa[c];
            v[i] = x;
        }
        float p = v[0]*v[0] + v[1]*v[1] + v[2]*v[2] + v[3]*v[3];
#pragma unroll
        for (int off = 1; off <= 16; off <<= 1) p += __shfl_xor(p, off, 64);
        if (c4 == 0) norm_l[q] = p;
        bf16x4 h; h[0]=(bf16_t)v[0]; h[1]=(bf16_t)v[1]; h[2]=(bf16_t)v[2]; h[3]=(bf16_t)v[3];
        const int off = q * DN + ((c4 * 4) ^ ((q & 7) << 3));
        *reinterpret_cast<bf16x4*>(&VT[off]) = h;
    }
    __syncthreads();   // ids_l ready (and VT in flight is fine until next barrier)

    // ---- stage Eg: gather 50 emb rows f32 -> bf16 LDS (swizzled); zero-pad ----
    for (int idx = tid; idx < NBRN * 32; idx += 256) {
        const int j = idx >> 5, c4 = idx & 31;
        const float4 f = *reinterpret_cast<const float4*>(emb + (size_t)ids_l[j] * DN + c4 * 4);
        bf16x4 h; h[0]=(bf16_t)f.x; h[1]=(bf16_t)f.y; h[2]=(bf16_t)f.z; h[3]=(bf16_t)f.w;
        *reinterpret_cast<bf16x4*>(&EgL[j * DN + ((c4 * 4) ^ ((j & 7) << 3))]) = h;
    }
    for (int idx = tid; idx < (MPAD - NBRN) * 32; idx += 256) {
        const int j = NBRN + (idx >> 5), c4 = idx & 31;
        bf16x4 z; z[0]=(bf16_t)0.f; z[1]=(bf16_t)0.f; z[2]=(bf16_t)0.f; z[3]=(bf16_t)0.f;
        *reinterpret_cast<bf16x4*>(&EgL[j * DN + ((c4 * 4) ^ ((j & 7) << 3))]) = z;
    }
    __syncthreads();   // Eg + VT staged

    // ---- GEMM1: L = leaky(Eg @ Wn + bn); B-frags straight from global WnT ----
    f32x4 accv[8];
#pragma unroll
    for (int nt = 0; nt < 8; ++nt) accv[nt] = (f32x4){0.f, 0.f, 0.f, 0.f};

#pragma unroll
    for (int ks = 0; ks < 4; ++ks) {
        const int row = w * 16 + l15;
        const int k0  = ks * 32 + l4 * 8;
        const bf16x8 a = *reinterpret_cast<const bf16x8*>(&EgL[row * DN + (k0 ^ ((row & 7) << 3))]);
#pragma unroll
        for (int nt = 0; nt < 8; ++nt) {
            const int n = nt * 16 + l15;
            const bf16x8 bfr = *reinterpret_cast<const bf16x8*>(WnT + n * DN + k0);
            accv[nt] = __builtin_amdgcn_mfma_f32_16x16x32_bf16(a, bfr, accv[nt], 0, 0, 0);
        }
    }

    // ---- epilogue: bias+leaky, ||L_j||^2 partials, store L (bf16, swizzled) ----
    float n2p[4] = {0.f, 0.f, 0.f, 0.f};
#pragma unroll
    for (int nt = 0; nt < 8; ++nt) {
        const int coln = nt * 16 + l15;
        const float bb = bn[coln];
#pragma unroll
        for (int r = 0; r < 4; ++r) {
            float v = leaky_f(accv[nt][r] + bb);
            n2p[r] += v * v;
            const int row = w * 16 + l4 * 4 + r;
            EgL[row * DN + (coln ^ ((row & 7) << 3))] = (bf16_t)v;
        }
    }
#pragma unroll
    for (int r = 0; r < 4; ++r) {
        float p = n2p[r];
#pragma unroll
        for (int off = 1; off <= 8; off <<= 1) p += __shfl_xor(p, off, 64);
        if (l15 == 0) n2_l[w * 16 + l4 * 4 + r] = p;
    }
    // (no barrier needed: each wave only reads back its own 16 rows of EgL)

    // ---- GEMM2: dots = L @ VT^T  (one 16-col tile; cols 0..7 valid) ----
    f32x4 dacc = (f32x4){0.f, 0.f, 0.f, 0.f};
#pragma unroll
    for (int ks = 0; ks < 4; ++ks) {
        const int row = w * 16 + l15;
        const int k0  = ks * 32 + l4 * 8;
        const bf16x8 a   = *reinterpret_cast<const bf16x8*>(&EgL[row * DN + (k0 ^ ((row & 7) << 3))]);
        const bf16x8 bfr = *reinterpret_cast<const bf16x8*>(&VT[l15 * DN + (k0 ^ ((l15 & 7) << 3))]);
        dacc = __builtin_amdgcn_mfma_f32_16x16x32_bf16(a, bfr, dacc, 0, 0, 0);
    }
#pragma unroll
    for (int r = 0; r < 4; ++r)
        dotL[w * 16 + l4 * 4 + r][l15] = dacc[r];
    __syncthreads();

    // ---- softmax + pos/neg/hete: single wave, lane j = neighbor j ----
    if (tid < 64) {
        const int j = tid;
        const bool act = j < NBRN;
        float mut = 0.0f, wj = 0.0f, hw = 0.0f;
        float mn[NEGN];
#pragma unroll
        for (int n = 0; n < NEGN; ++n) mn[n] = 0.0f;
        int mk = 0;
        float x = NEG_INF_F;
        if (act) {
            const float n2 = n2_l[j];
            const float dj = 2.0f * dotL[j][0] - norm_l[0] - n2;
            mut            = 2.0f * dotL[j][1] - norm_l[1] - n2;
#pragma unroll
            for (int n = 0; n < NEGN; ++n) mn[n] = 2.0f * dotL[j][2 + n] - norm_l[2 + n] - n2;
            hw = dotL[j][7];
            mk = mask_p[base + j];
            wj = w_p[base + j];
            x = mk ? dj : NEG_INF_F;
        }
        const float m  = wave_max(x);
        const float ex = act ? __expf(x - m) : 0.0f;   // exactly 50 summands, like reference
        const float S  = wave_sum(ex);
        const float atts  = ex / S;
        const float atts2 = (act && mk) ? atts : 0.0f;
        const float nw = atts2 * wj;
        const float posv = wave_sum(nw * mut);
        float nsum[NEGN];
#pragma unroll
        for (int n = 0; n < NEGN; ++n) nsum[n] = wave_sum(nw * mn[n]);
        const float wsum = wave_sum(act ? wj : 0.0f);
        const float msum = wave_sum(act ? (float)mk : 0.0f);
        const float hsum = wave_sum(atts2 * hw);       // = avg_embed . Wa
        if (tid == 0) {
            const float nbr_n = fminf(fmaxf(msum, 1.0f), (float)NBRN);
            const float ave_w = wsum / nbr_n;
            const int o = (side * EN + e) * BN + b;
            posW[o]  = posv;
            heteW[o] = leaky_f(ave_w * hsum + ba[0]);
#pragma unroll
            for (int n = 0; n < NEGN; ++n) negW[(size_t)o * NEGN + n] = nsum[n];
        }
    }
}

// ---------------------------------------------------------------------------
// Kernel 3: allpos[side][e] = all_b(flags[e][b] > 0)
// ---------------------------------------------------------------------------
__global__ __launch_bounds__(256) void allpos_kernel(
    const int* __restrict__ s_flags, const int* __restrict__ t_flags, int* __restrict__ allpos)
{
    const int side = blockIdx.x >> 2, e = blockIdx.x & 3;
    const int* f = side ? t_flags : s_flags;
    int ok = 1;
    for (int b = threadIdx.x; b < BN; b += 256) ok &= (f[e * BN + b] > 0);
    ok = __syncthreads_and(ok);
    if (threadIdx.x == 0) allpos[blockIdx.x] = ok;
}

// ---------------------------------------------------------------------------
// Kernel 4: per-b loss partial (mu, neg_mus, double-softmax over E, log-sigmoids)
// ---------------------------------------------------------------------------
__global__ __launch_bounds__(64) void loss_kernel(
    const int* __restrict__ e_types, const float* __restrict__ ete,
    const int* __restrict__ s_flags, const int* __restrict__ t_flags,
    const float* __restrict__ sE, const float* __restrict__ tE,
    const float* __restrict__ negS, const float* __restrict__ negT,
    const float* __restrict__ posW, const float* __restrict__ heteW,
    const float* __restrict__ negW, const int* __restrict__ allpos,
    float* __restrict__ partials)
{
    const int b = blockIdx.x;
    const int lane = threadIdx.x;   // 64 lanes, each covers dims lane and lane+64
    const int et = e_types[b];

    const float se0 = sE[(size_t)b * DN + lane],      se1 = sE[(size_t)b * DN + lane + 64];
    const float te0 = tE[(size_t)b * DN + lane],      te1 = tE[(size_t)b * DN + lane + 64];
    const float ee0 = ete[et * DN + lane],            ee1 = ete[et * DN + lane + 64];

    float d0 = se0 + ee0 - te0, d1 = se1 + ee1 - te1;
    const float mu = -wave_sum(d0 * d0 + d1 * d1);

    float nmst[NEGN], nmts[NEGN];
#pragma unroll
    for (int n = 0; n < NEGN; ++n) {
        const float* nt = negT + ((size_t)b * NEGN + n) * DN;
        const float* ns = negS + ((size_t)b * NEGN + n) * DN;
        float a0 = se0 - nt[lane], a1 = se1 - nt[lane + 64];
        nmst[n] = -wave_sum(a0 * a0 + a1 * a1);
        float c0 = te0 - ns[lane], c1 = te1 - ns[lane + 64];
        nmts[n] = -wave_sum(c0 * c0 + c1 * c1);
    }

    if (lane == 0) {
        float posl[2];
        float negl[2][NEGN];
        for (int side = 0; side < 2; ++side) {
            const int* fl = side ? t_flags : s_flags;
            float att[EN], pv[EN];
            int mk[EN], ap[EN];
#pragma unroll
            for (int ei = 0; ei < EN; ++ei) {
                ap[ei] = allpos[side * EN + ei];
                mk[ei] = fl[ei * BN + b] > 0;
                const int o = (side * EN + ei) * BN + b;
                att[ei] = ap[ei] ? 0.0f : heteW[o];
                pv[ei]  = ap[ei] ? 0.0f : posW[o];
            }
            // softmax 1: where(mask, att, NEG_INF)
            float x[EN], m = NEG_INF_F;
#pragma unroll
            for (int ei = 0; ei < EN; ++ei) { x[ei] = mk[ei] ? att[ei] : NEG_INF_F; m = fmaxf(m, x[ei]); }
            float s = 0.0f, ex[EN];
#pragma unroll
            for (int ei = 0; ei < EN; ++ei) { ex[ei] = __expf(x[ei] - m); s += ex[ei]; }
            float v1[EN];
#pragma unroll
            for (int ei = 0; ei < EN; ++ei) v1[ei] = ex[ei] / s;
            // softmax 2: softmax(where(mask, v1, 0.0))  (no output masking!)
            float y[EN], m2 = NEG_INF_F;
#pragma unroll
            for (int ei = 0; ei < EN; ++ei) { y[ei] = mk[ei] ? v1[ei] : 0.0f; m2 = fmaxf(m2, y[ei]); }
            float s2 = 0.0f, ex2[EN];
#pragma unroll
            for (int ei = 0; ei < EN; ++ei) { ex2[ei] = __expf(y[ei] - m2); s2 += ex2[ei]; }
            float pl = 0.0f;
            float nl[NEGN];
#pragma unroll
            for (int n = 0; n < NEGN; ++n) nl[n] = 0.0f;
#pragma unroll
            for (int ei = 0; ei < EN; ++ei) {
                const float na = ex2[ei] / s2;
                pl += na * pv[ei];
                const int o = (side * EN + ei) * BN + b;
#pragma unroll
                for (int n = 0; n < NEGN; ++n) {
                    const float nv = ap[ei] ? 0.0f : negW[(size_t)o * NEGN + n];
                    nl[n] += na * nv;
                }
            }
            posl[side] = pl;
#pragma unroll
            for (int n = 0; n < NEGN; ++n) negl[side][n] = nl[n];
        }

        const float lam = mu + posl[0] + posl[1];
        float total = -logf(sigmoid_f(lam) + 1e-6f) / (float)BN;
#pragma unroll
        for (int n = 0; n < NEGN; ++n) {
            total += -logf(sigmoid_f(-(nmst[n] + negl[0][n])) + 1e-6f) / (float)(BN * NEGN);
            total += -logf(sigmoid_f(-(nmts[n] + negl[1][n])) + 1e-6f) / (float)(BN * NEGN);
        }
        partials[b] = total;
    }
}

// ---------------------------------------------------------------------------
// Kernel 5: reduce partials + NORM_RATE * sum(ete^2) -> d_out[0]
// ---------------------------------------------------------------------------
__global__ __launch_bounds__(256) void final_kernel(
    const float* __restrict__ partials, const float* __restrict__ ete, float* __restrict__ out)
{
    __shared__ float red[256];
    const int tid = threadIdx.x;
    float s = 0.0f;
    for (int i = tid; i < BN; i += 256) s += partials[i];
    float t = 0.0f;
    for (int i = tid; i < EN * DN; i += 256) { const float v = ete[i]; t += v * v; }
    red[tid] = s + 1e-4f * t;
    __syncthreads();
    for (int st = 128; st > 0; st >>= 1) {
        if (tid < st) red[tid] += red[tid + st];
        __syncthreads();
    }
    if (tid == 0) out[0] = red[0];
}

// ---------------------------------------------------------------------------
extern "C" void kernel_launch(void* const* d_in, const int* in_sizes, int n_in,
                              void* d_out, int out_size, void* d_ws, size_t ws_size,
                              hipStream_t stream)
{
    const int*   e_types   = (const int*)  d_in[0];
    const int*   s_ids     = (const int*)  d_in[1];
    // d_in[2] s_types: inert
    const int*   s_negs    = (const int*)  d_in[3];
    const int*   s_nbr_ids = (const int*)  d_in[4];
    const int*   s_nbr_msk = (const int*)  d_in[5];
    const float* s_nbr_w   = (const float*)d_in[6];
    const int*   s_flags   = (const int*)  d_in[7];
    const int*   t_ids     = (const int*)  d_in[8];
    // d_in[9] t_types: inert
    const int*   t_negs    = (const int*)  d_in[10];
    const int*   t_nbr_ids = (const int*)  d_in[11];
    const int*   t_nbr_msk = (const int*)  d_in[12];
    const float* t_nbr_w   = (const float*)d_in[13];
    const int*   t_flags   = (const int*)  d_in[14];
    const float* emb       = (const float*)d_in[15];
    const float* ete       = (const float*)d_in[16];
    const float* W_node    = (const float*)d_in[17];
    const float* b_node    = (const float*)d_in[18];
    const float* W_nbr     = (const float*)d_in[19];
    const float* b_nbr     = (const float*)d_in[20];
    const float* W_att     = (const float*)d_in[21];
    const float* b_att     = (const float*)d_in[22];

    // workspace layout (floats)
    float* ws   = (float*)d_ws;
    float* sE   = ws;                                   // B*D
    float* tE   = sE   + (size_t)BN * DN;               // B*D
    float* negS = tE   + (size_t)BN * DN;               // B*NEG*D
    float* negT = negS + (size_t)BN * NEGN * DN;        // B*NEG*D
    float* posW = negT + (size_t)BN * NEGN * DN;        // 2*E*B
    float* heteW= posW + (size_t)2 * EN * BN;           // 2*E*B
    float* negW = heteW+ (size_t)2 * EN * BN;           // 2*E*B*NEG
    float* parts= negW + (size_t)2 * EN * BN * NEGN;    // B
    int*   apos = (int*)(parts + BN);                   // 8 ints
    bf16_t* WnT = (bf16_t*)(apos + 8);                  // 128*128 bf16 (32KB)

    prep_kernel<<<(DN * DN + 255) / 256, 256, 0, stream>>>(W_nbr, WnT);

    latent_kernel<<<(2 * BN + 2 * BN * NEGN) / 8, 128, 0, stream>>>(
        emb, W_node, b_node, s_ids, t_ids, s_negs, t_negs, sE, tE, negS, negT);

    edge_kernel<<<2 * EN * BN, 256, 0, stream>>>(
        emb, ete, WnT, b_nbr, W_att, b_att,
        s_nbr_ids, s_nbr_msk, s_nbr_w,
        t_nbr_ids, t_nbr_msk, t_nbr_w,
        sE, tE, negS, negT, posW, heteW, negW);

    allpos_kernel<<<8, 256, 0, stream>>>(s_flags, t_flags, apos);

    loss_kernel<<<BN, 64, 0, stream>>>(
        e_types, ete, s_flags, t_flags, sE, tE, negS, negT,
        posW, heteW, negW, apos, parts);

    final_kernel<<<1, 256, 0, stream>>>(parts, ete, (float*)d_out);
}